// Round 9
// baseline (1216.331 us; speedup 1.0000x reference)
//
#include <hip/hip_runtime.h>
#include <math.h>

#define N_NODES 100000
#define N_EDGES 3200000
#define N_FEAT  512
#define N_HID   16
#define N_CLS   40

#define BUCKET_SHIFT 9          // 512 nodes per bucket
#define NB 196                  // ceil(100000/512)
#define NB_PAD 256
#define BIN_CHUNK 4096          // edges per k_bin block (16 per thread)
#define CAP 17408               // slots per bucket region (mean 16384, +8 sigma)

// ---------------- zero fill (float4) ----------------
__global__ void k_zero(float4* __restrict__ p, int n4) {
    int i = blockIdx.x * 256 + threadIdx.x;
    if (i < n4) p[i] = make_float4(0.f, 0.f, 0.f, 0.f);
}

// ---------------- zero fill (ints) ----------------
__global__ void k_zero_i(int* __restrict__ p, int n) {
    int i = blockIdx.x * 256 + threadIdx.x;
    if (i < n) p[i] = 0;
}

// ---------------- pass A: bin edges into fixed-CAP bucket regions ----------
// Per block: LDS bucket histogram -> one global ticket per touched bucket ->
// clustered writes. Record packs (src | dstlo<<17, w_bits): src<2^17, dstlo<2^9.
// curb[b] ends up = total records in bucket b. dst cached in registers
// between phase 1 and phase 3 (saves a 12.8 MB re-read).
__global__ __launch_bounds__(256) void k_bin(const int* __restrict__ src,
                                             const int* __restrict__ dst,
                                             const float* __restrict__ ew,
                                             int* __restrict__ curb,
                                             int2* __restrict__ bin) {
    __shared__ int lcnt[NB];
    __shared__ int lbase[NB];
    const int tid = threadIdx.x;
    const int e0 = blockIdx.x * BIN_CHUNK;
    if (tid < NB) lcnt[tid] = 0;
    __syncthreads();
    int dreg[16];
    // phase 1: local bucket histogram (cache dst)
    #pragma unroll
    for (int u = 0; u < 16; ++u) {
        int e = e0 + u * 256 + tid;
        dreg[u] = (e < N_EDGES) ? dst[e] : -1;
        if (dreg[u] >= 0) atomicAdd(&lcnt[dreg[u] >> BUCKET_SHIFT], 1);
    }
    __syncthreads();
    // phase 2: reserve a contiguous run in the bucket's fixed region
    if (tid < NB) {
        int c = lcnt[tid];
        lbase[tid] = (c > 0) ? (tid * CAP + atomicAdd(&curb[tid], c)) : 0;
        lcnt[tid] = 0;
    }
    __syncthreads();
    // phase 3: write records into the reserved runs
    #pragma unroll
    for (int u = 0; u < 16; ++u) {
        int e = e0 + u * 256 + tid;
        if (dreg[u] >= 0) {
            int d = dreg[u];
            int b = d >> BUCKET_SHIFT;
            int rank = atomicAdd(&lcnt[b], 1);
            bin[lbase[b] + rank] =
                make_int2(src[e] | ((d & 511) << 17), __float_as_int(ew[e]));
        }
    }
}

// ---------------- direct aggregation from bin (no CSR, no place pass) ----------
// Block (b,q) owns nodes [b*512 + q*128, +128); scans bucket b's records
// (broadcast 8B loads), gathers tab[src] + LDS-atomicAdd only for its quarter.
// Each record is gathered exactly once chip-wide. RELU=1 fuses bias+relu.
template <int RELU>
__global__ __launch_bounds__(256) void k_aggd(const int* __restrict__ curb,
                                              const int2* __restrict__ bin,
                                              const float* __restrict__ tab,
                                              const float* __restrict__ bias,
                                              float* __restrict__ out) {
    __shared__ float acc[128 * 16];           // 8 KB
    const int bq  = blockIdx.x;
    const int b   = bq >> 2;
    const int q   = bq & 3;
    const int tid = threadIdx.x;
    #pragma unroll
    for (int u = 0; u < 8; ++u) acc[tid + u * 256] = 0.f;
    __syncthreads();
    const int c = curb[b];
    const int2* bp = bin + (size_t)b * CAP;
    const int qw = tid >> 4;                  // 16 quarter-wave streams
    const int j  = tid & 15;                  // feature lane
    int i = qw;
    for (; i + 16 < c; i += 32) {             // 2 records in flight per stream
        const int2 rA = bp[i];
        const int2 rB = bp[i + 16];
        const int dA = (rA.x >> 17) & 511;
        const int dB = (rB.x >> 17) & 511;
        if ((dA >> 7) == q) {
            float g = tab[(rA.x & 0x1FFFF) * N_HID + j];
            atomicAdd(&acc[(dA & 127) * 16 + j], __int_as_float(rA.y) * g);
        }
        if ((dB >> 7) == q) {
            float g = tab[(rB.x & 0x1FFFF) * N_HID + j];
            atomicAdd(&acc[(dB & 127) * 16 + j], __int_as_float(rB.y) * g);
        }
    }
    if (i < c) {
        const int2 rA = bp[i];
        const int dA = (rA.x >> 17) & 511;
        if ((dA >> 7) == q) {
            float g = tab[(rA.x & 0x1FFFF) * N_HID + j];
            atomicAdd(&acc[(dA & 127) * 16 + j], __int_as_float(rA.y) * g);
        }
    }
    __syncthreads();
    const int node0 = (b << BUCKET_SHIFT) + (q << 7);
    #pragma unroll
    for (int u = 0; u < 8; ++u) {
        int idx = tid + u * 256;              // 0..2047 over 128 nodes x 16
        int node = node0 + (idx >> 4);
        int jj = idx & 15;
        if (node < N_NODES) {
            float v = acc[idx];
            if (RELU) v = fmaxf(v + bias[jj], 0.f);
            out[node * N_HID + jj] = v;
        }
    }
}

// ---------------- GEMM1: support1[N,16] = X[N,512] @ W1[512,16] ----------------
// quarter-wave (16 lanes) per 4 rows, k split across the 16 lanes.
// #pragma unroll 1 on the K-chunk loop prevents the load-hoist VGPR blowup.
#define FMA16(A, F, W0, W1v, W2v, W3v)                                   \
    A[0] += F * W0.x;  A[1] += F * W0.y;  A[2]  += F * W0.z;  A[3]  += F * W0.w;  \
    A[4] += F * W1v.x; A[5] += F * W1v.y; A[6]  += F * W1v.z; A[7]  += F * W1v.w; \
    A[8] += F * W2v.x; A[9] += F * W2v.y; A[10] += F * W2v.z; A[11] += F * W2v.w; \
    A[12]+= F * W3v.x; A[13]+= F * W3v.y; A[14] += F * W3v.z; A[15] += F * W3v.w;

__global__ __launch_bounds__(256) void k_gemm1(const float* __restrict__ x,
                                               const float* __restrict__ W1,
                                               float* __restrict__ out) {
    __shared__ float Wl[512 * 16];
    const int tid = threadIdx.x;
    #pragma unroll
    for (int u = 0; u < 32; ++u) {
        int idx = tid + u * 256;          // over W1[512][16]
        int k = idx >> 4, j = idx & 15;
        int slot = (j >> 2) ^ ((k >> 2) & 3);
        Wl[k * 16 + slot * 4 + (j & 3)] = W1[idx];
    }
    __syncthreads();

    const int sub  = tid & 15;            // k-slice owner within quarter-wave
    const int grp  = tid >> 4;            // 0..15: quarter-wave id in block
    const int rbase = blockIdx.x * 64 + grp * 4;

    const int r0 = min(rbase + 0, N_NODES - 1);
    const int r1 = min(rbase + 1, N_NODES - 1);
    const int r2 = min(rbase + 2, N_NODES - 1);
    const int r3 = min(rbase + 3, N_NODES - 1);
    const float* xp0 = x + (size_t)r0 * N_FEAT + sub * 4;
    const float* xp1 = x + (size_t)r1 * N_FEAT + sub * 4;
    const float* xp2 = x + (size_t)r2 * N_FEAT + sub * 4;
    const float* xp3 = x + (size_t)r3 * N_FEAT + sub * 4;

    float a0[16], a1[16], a2[16], a3[16];
    #pragma unroll
    for (int j = 0; j < 16; ++j) { a0[j] = 0.f; a1[j] = 0.f; a2[j] = 0.f; a3[j] = 0.f; }

    const int sw = sub & 3;               // = (k>>2)&3 for this lane's k's

    #pragma unroll 1
    for (int i = 0; i < 8; ++i) {
        const float4 xa = *(const float4*)(xp0 + i * 64);
        const float4 xb = *(const float4*)(xp1 + i * 64);
        const float4 xc = *(const float4*)(xp2 + i * 64);
        const float4 xd = *(const float4*)(xp3 + i * 64);
        const int kb = i * 64 + sub * 4;
        #pragma unroll
        for (int t = 0; t < 4; ++t) {
            const float* wr = &Wl[(kb + t) * 16];
            const float4 w0 = *(const float4*)(wr + ((0 ^ sw) << 2));
            const float4 w1 = *(const float4*)(wr + ((1 ^ sw) << 2));
            const float4 w2 = *(const float4*)(wr + ((2 ^ sw) << 2));
            const float4 w3 = *(const float4*)(wr + ((3 ^ sw) << 2));
            const float fa = (t == 0) ? xa.x : (t == 1) ? xa.y : (t == 2) ? xa.z : xa.w;
            const float fb = (t == 0) ? xb.x : (t == 1) ? xb.y : (t == 2) ? xb.z : xb.w;
            const float fc = (t == 0) ? xc.x : (t == 1) ? xc.y : (t == 2) ? xc.z : xc.w;
            const float fd = (t == 0) ? xd.x : (t == 1) ? xd.y : (t == 2) ? xd.z : xd.w;
            FMA16(a0, fa, w0, w1, w2, w3)
            FMA16(a1, fb, w0, w1, w2, w3)
            FMA16(a2, fc, w0, w1, w2, w3)
            FMA16(a3, fd, w0, w1, w2, w3)
        }
    }

    // butterfly reduce over the 16-lane group (xor bits 0..3 of lane)
    #pragma unroll
    for (int m = 1; m <= 8; m <<= 1) {
        #pragma unroll
        for (int j = 0; j < 16; ++j) {
            a0[j] += __shfl_xor(a0[j], m, 64);
            a1[j] += __shfl_xor(a1[j], m, 64);
            a2[j] += __shfl_xor(a2[j], m, 64);
            a3[j] += __shfl_xor(a3[j], m, 64);
        }
    }

    // lane `sub` writes column j = sub of its 4 rows (static-index select)
    float v0 = a0[0], v1 = a1[0], v2 = a2[0], v3 = a3[0];
    #pragma unroll
    for (int j = 1; j < 16; ++j) {
        const bool p = (sub == j);
        v0 = p ? a0[j] : v0;
        v1 = p ? a1[j] : v1;
        v2 = p ? a2[j] : v2;
        v3 = p ? a3[j] : v3;
    }
    if (rbase + 0 < N_NODES) out[(rbase + 0) * N_HID + sub] = v0;
    if (rbase + 1 < N_NODES) out[(rbase + 1) * N_HID + sub] = v1;
    if (rbase + 2 < N_NODES) out[(rbase + 2) * N_HID + sub] = v2;
    if (rbase + 3 < N_NODES) out[(rbase + 3) * N_HID + sub] = v3;
}

// ======== fallback (direct atomic scatter) ========
__global__ __launch_bounds__(256) void k_edge(const int* __restrict__ src,
                                              const int* __restrict__ dst,
                                              const float* __restrict__ ew,
                                              const float* __restrict__ tab,
                                              float* __restrict__ out) {
    int gid = blockIdx.x * 256 + threadIdx.x;
    int e = gid >> 2;
    if (e >= N_EDGES) return;
    int j4 = (gid & 3) << 2;
    int s = src[e];
    int d = dst[e];
    float w = ew[e];
    const float4 v = *(const float4*)&tab[s * N_HID + j4];
    float* o = &out[d * N_HID + j4];
    atomicAdd(o + 0, v.x * w);
    atomicAdd(o + 1, v.y * w);
    atomicAdd(o + 2, v.z * w);
    atomicAdd(o + 3, v.w * w);
}

__global__ void k_relu_bias(float* __restrict__ h, const float* __restrict__ b1) {
    int i = blockIdx.x * 256 + threadIdx.x;
    if (i >= N_NODES * 4) return;
    float4 v = ((float4*)h)[i];
    int jb = (i & 3) << 2;
    v.x = fmaxf(v.x + b1[jb + 0], 0.f);
    v.y = fmaxf(v.y + b1[jb + 1], 0.f);
    v.z = fmaxf(v.z + b1[jb + 2], 0.f);
    v.w = fmaxf(v.w + b1[jb + 3], 0.f);
    ((float4*)h)[i] = v;
}

// ---------------- out = log_softmax(agg2 @ W2 + b2) ----------------
__global__ __launch_bounds__(256) void k_out(const float* __restrict__ agg2,
                                             const float* __restrict__ W2,
                                             const float* __restrict__ b2,
                                             float* __restrict__ out) {
    int row  = (blockIdx.x * 256 + threadIdx.x) >> 6;
    int lane = threadIdx.x & 63;
    if (row >= N_NODES) return;

    const float* a = &agg2[row * N_HID];
    float av[16];
    #pragma unroll
    for (int k = 0; k < 16; k += 4) {
        float4 t = *(const float4*)&a[k];
        av[k + 0] = t.x; av[k + 1] = t.y; av[k + 2] = t.z; av[k + 3] = t.w;
    }

    int c = (lane < N_CLS) ? lane : 0;
    float acc = b2[c];
    #pragma unroll
    for (int k = 0; k < 16; ++k)
        acc = fmaf(av[k], W2[k * N_CLS + c], acc);

    float mval = (lane < N_CLS) ? acc : -INFINITY;
    #pragma unroll
    for (int m = 32; m; m >>= 1) mval = fmaxf(mval, __shfl_xor(mval, m, 64));
    float ex = (lane < N_CLS) ? expf(acc - mval) : 0.f;
    float s = ex;
    #pragma unroll
    for (int m = 32; m; m >>= 1) s += __shfl_xor(s, m, 64);
    float ls = logf(s);
    if (lane < N_CLS) out[row * N_CLS + lane] = acc - mval - ls;
}

extern "C" void kernel_launch(void* const* d_in, const int* in_sizes, int n_in,
                              void* d_out, int out_size, void* d_ws, size_t ws_size,
                              hipStream_t stream) {
    const float* x    = (const float*)d_in[0];
    const int*   esrc = (const int*)  d_in[1];
    const int*   edst = (const int*)  d_in[2];
    const float* ew   = (const float*)d_in[3];
    const float* W1   = (const float*)d_in[4];
    const float* b1   = (const float*)d_in[5];
    const float* W2   = (const float*)d_in[6];
    const float* b2   = (const float*)d_in[7];
    float* out = (float*)d_out;

    // ---- tier-1 workspace layout, 4-byte units ----
    // bin  : NB*CAP int2 = 27.3 MB (live through both agg passes)
    // buf0 : 1.6M floats (support1 / agg2)
    // buf1 : 1.6M floats (h)
    // curb : NB_PAD ints
    int* ws = (int*)d_ws;
    int2*  bin  = (int2*)ws;
    float* buf0 = (float*)(ws + 2 * (size_t)NB * CAP);
    float* buf1 = buf0 + (size_t)N_NODES * N_HID;
    int*   curb = (int*)(buf1 + (size_t)N_NODES * N_HID);
    const size_t need1 = ((size_t)(curb + NB_PAD) - (size_t)d_ws);

    const int n4 = N_NODES * 4;
    const int zgrid = (n4 + 255) / 256;

    if (ws_size >= need1) {
        // ---- tier 1: bin + direct bucket-LDS aggregation ----
        k_zero_i<<<1, 256, 0, stream>>>(curb, NB_PAD);
        k_bin<<<(N_EDGES + BIN_CHUNK - 1) / BIN_CHUNK, 256, 0, stream>>>(
            esrc, edst, ew, curb, bin);
        // support1 = X @ W1
        k_gemm1<<<(N_NODES + 63) / 64, 256, 0, stream>>>(x, W1, buf0);
        // h = relu(agg(support1) + b1)
        k_aggd<1><<<NB * 4, 256, 0, stream>>>(curb, bin, buf0, b1, buf1);
        // agg2 = agg(h)
        k_aggd<0><<<NB * 4, 256, 0, stream>>>(curb, bin, buf1, b1 /*unused*/, buf0);
        // out = log_softmax(agg2 @ W2 + b2)
        k_out<<<(N_NODES + 3) / 4, 256, 0, stream>>>(buf0, W2, b2, out);
        return;
    }

    // ---- fallback: atomic path (12.8 MB) ----
    {
        float* fb0 = (float*)d_ws;
        float* fb1 = fb0 + (size_t)N_NODES * N_HID;
        k_zero<<<zgrid, 256, 0, stream>>>((float4*)fb1, n4);
        k_gemm1<<<(N_NODES + 63) / 64, 256, 0, stream>>>(x, W1, fb0);
        k_edge<<<(N_EDGES * 4 + 255) / 256, 256, 0, stream>>>(esrc, edst, ew, fb0, fb1);
        k_relu_bias<<<zgrid, 256, 0, stream>>>(fb1, b1);
        k_zero<<<zgrid, 256, 0, stream>>>((float4*)fb0, n4);
        k_edge<<<(N_EDGES * 4 + 255) / 256, 256, 0, stream>>>(esrc, edst, ew, fb1, fb0);
        k_out<<<(N_NODES + 3) / 4, 256, 0, stream>>>(fb0, W2, b2, out);
    }
}

// Round 10
// 573.721 us; speedup vs baseline: 2.1201x; 2.1201x over previous
//
#include <hip/hip_runtime.h>
#include <math.h>

#define N_NODES 100000
#define N_EDGES 3200000
#define N_FEAT  512
#define N_HID   16
#define N_CLS   40

#define CNT_PAD 100352          // N_NODES rounded up (alignment slack)
#define SCAN_BLK 4096           // elements scanned per block (256 thr * 16)
#define N_SCAN_BLKS 25          // ceil(100000/4096)

#define BUCKET_SHIFT 9          // 512 nodes per bucket
#define NB 196                  // ceil(100000/512)
#define NB_PAD 256
#define BIN_CHUNK 4096          // edges per k_bin block (16 per thread)
#define CAP 17408               // slots per bucket region (mean 16384, +8 sigma)

// ---------------- zero fill (float4) ----------------
__global__ void k_zero(float4* __restrict__ p, int n4) {
    int i = blockIdx.x * 256 + threadIdx.x;
    if (i < n4) p[i] = make_float4(0.f, 0.f, 0.f, 0.f);
}

// ---------------- zero fill (ints) ----------------
__global__ void k_zero_i(int* __restrict__ p, int n) {
    int i = blockIdx.x * 256 + threadIdx.x;
    if (i < n) p[i] = 0;
}

// ---------------- pass A: bin edges into fixed-CAP bucket regions ----------
// Per block: LDS bucket histogram -> one global ticket per touched bucket ->
// clustered writes. Record packs (src | dstlo<<17, w_bits): src<2^17, dstlo<2^9.
// curb[b] ends up = total records in bucket b. dst cached in registers
// between phase 1 and phase 3 (saves a 12.8 MB re-read).
__global__ __launch_bounds__(256) void k_bin(const int* __restrict__ src,
                                             const int* __restrict__ dst,
                                             const float* __restrict__ ew,
                                             int* __restrict__ curb,
                                             int2* __restrict__ bin) {
    __shared__ int lcnt[NB];
    __shared__ int lbase[NB];
    const int tid = threadIdx.x;
    const int e0 = blockIdx.x * BIN_CHUNK;
    if (tid < NB) lcnt[tid] = 0;
    __syncthreads();
    int dreg[16];
    // phase 1: local bucket histogram (cache dst)
    #pragma unroll
    for (int u = 0; u < 16; ++u) {
        int e = e0 + u * 256 + tid;
        dreg[u] = (e < N_EDGES) ? dst[e] : -1;
        if (dreg[u] >= 0) atomicAdd(&lcnt[dreg[u] >> BUCKET_SHIFT], 1);
    }
    __syncthreads();
    // phase 2: reserve a contiguous run in the bucket's fixed region
    if (tid < NB) {
        int c = lcnt[tid];
        lbase[tid] = (c > 0) ? (tid * CAP + atomicAdd(&curb[tid], c)) : 0;
        lcnt[tid] = 0;
    }
    __syncthreads();
    // phase 3: write records into the reserved runs
    #pragma unroll
    for (int u = 0; u < 16; ++u) {
        int e = e0 + u * 256 + tid;
        if (dreg[u] >= 0) {
            int d = dreg[u];
            int b = d >> BUCKET_SHIFT;
            int rank = atomicAdd(&lcnt[b], 1);
            bin[lbase[b] + rank] =
                make_int2(src[e] | ((d & 511) << 17), __float_as_int(ew[e]));
        }
    }
}

// ---------------- scan of bucket totals -> global CSR base per bucket ----------
__global__ void k_bscan(const int* __restrict__ curb, int* __restrict__ bbase) {
    if (threadIdx.x == 0) {
        int run = 0;
        for (int b = 0; b < NB; ++b) { bbase[b] = run; run += curb[b]; }
    }
}

// ---------------- pass B: per-bucket count + scan + compact into srt ----------
// One block per bucket. Produces start[]/cnt[] and srt (node-sorted compact
// CSR). Bucket srt window ~136 KB: L2-resident.
__global__ __launch_bounds__(256) void k_place2(const int* __restrict__ curb,
                                                const int* __restrict__ bbase,
                                                const int2* __restrict__ bin,
                                                int2* __restrict__ srt,
                                                int* __restrict__ start,
                                                int* __restrict__ cnt) {
    __shared__ int lcnt[512];
    __shared__ int lpre[512];
    __shared__ int lcur[512];
    __shared__ int ssum[256];
    const int b = blockIdx.x;
    const int tid = threadIdx.x;
    lcnt[tid] = 0; lcnt[tid + 256] = 0;
    lcur[tid] = 0; lcur[tid + 256] = 0;
    __syncthreads();
    const int c = curb[b];
    const int2* bp = bin + (size_t)b * CAP;
    // per-node counts within the bucket
    for (int i = tid; i < c; i += 256)
        atomicAdd(&lcnt[(bp[i].x >> 17) & 511], 1);
    __syncthreads();
    // exclusive scan of lcnt[512]: pair-sum -> 256-wide Hillis-Steele -> expand
    const int p0 = lcnt[2 * tid], p1 = lcnt[2 * tid + 1];
    ssum[tid] = p0 + p1;
    __syncthreads();
    for (int off = 1; off < 256; off <<= 1) {
        int t = (tid >= off) ? ssum[tid - off] : 0;
        __syncthreads();
        ssum[tid] += t;
        __syncthreads();
    }
    const int ex = (tid > 0) ? ssum[tid - 1] : 0;
    lpre[2 * tid] = ex;
    lpre[2 * tid + 1] = ex + p0;
    __syncthreads();
    // emit start/cnt (coalesced)
    const int node0 = b << BUCKET_SHIFT;
    const int gb = bbase[b];
    for (int i = tid; i < 512; i += 256) {
        int node = node0 + i;
        if (node < N_NODES) { start[node] = gb + lpre[i]; cnt[node] = lcnt[i]; }
    }
    // scatter records to node-sorted positions
    for (int i = tid; i < c; i += 256) {
        int2 rec = bp[i];
        int dlo = (rec.x >> 17) & 511;
        int rank = atomicAdd(&lcur[dlo], 1);
        srt[gb + lpre[dlo] + rank] = make_int2(rec.x & 0x1FFFF, rec.y);
    }
}

// ---------------- CSR aggregation: out[n,j] = sum_{e: dst=n} w_e * tab[src_e, j] ----
// v2: 32 lanes per node — two 16-lane halves process interleaved 4-record
// groups (half 0: [0,4)+[8,12)+..., half 1: [4,8)+[12,16)+...), then merge
// via one shfl_xor(16). Halves the per-node serial gather chain and doubles
// wave-level parallelism vs the 16-lane version. RELU=1 fuses bias+relu.
template <int RELU>
__global__ __launch_bounds__(256) void k_agg(const int* __restrict__ start,
                                             const int* __restrict__ cnt,
                                             const int2* __restrict__ srt,
                                             const float* __restrict__ tab,
                                             const float* __restrict__ bias,
                                             float* __restrict__ out) {
    int gid = blockIdx.x * 256 + threadIdx.x;
    int node = gid >> 5;
    if (node >= N_NODES) return;
    const int half = (gid >> 4) & 1;
    const int j = gid & 15;
    const int s0 = start[node];
    const int len = cnt[node];
    float a0 = 0.f, a1 = 0.f, a2 = 0.f, a3 = 0.f;
    const int nf8 = len & ~7;
    for (int base = half * 4; base + 4 <= nf8; base += 8) {
        int2 e0 = srt[s0 + base + 0];
        int2 e1 = srt[s0 + base + 1];
        int2 e2 = srt[s0 + base + 2];
        int2 e3 = srt[s0 + base + 3];
        a0 += __int_as_float(e0.y) * tab[e0.x * N_HID + j];
        a1 += __int_as_float(e1.y) * tab[e1.x * N_HID + j];
        a2 += __int_as_float(e2.y) * tab[e2.x * N_HID + j];
        a3 += __int_as_float(e3.y) * tab[e3.x * N_HID + j];
    }
    // tail (< 8 records): half 0 takes the first up-to-4, half 1 the rest
    const int tb = nf8 + half * 4;
    const int te = min(len, tb + 4);
    for (int k = tb; k < te; ++k) {
        int2 e = srt[s0 + k];
        a0 += __int_as_float(e.y) * tab[e.x * N_HID + j];
    }
    float v = (a0 + a2) + (a1 + a3);
    v += __shfl_xor(v, 16, 64);          // merge the two halves
    if (half == 0) {
        if (RELU) v = fmaxf(v + bias[j], 0.f);
        out[node * N_HID + j] = v;
    }
}

// ---------------- GEMM1: support1[N,16] = X[N,512] @ W1[512,16] ----------------
// quarter-wave (16 lanes) per 4 rows, k split across the 16 lanes.
// #pragma unroll 1 on the K-chunk loop prevents the load-hoist VGPR blowup.
#define FMA16(A, F, W0, W1v, W2v, W3v)                                   \
    A[0] += F * W0.x;  A[1] += F * W0.y;  A[2]  += F * W0.z;  A[3]  += F * W0.w;  \
    A[4] += F * W1v.x; A[5] += F * W1v.y; A[6]  += F * W1v.z; A[7]  += F * W1v.w; \
    A[8] += F * W2v.x; A[9] += F * W2v.y; A[10] += F * W2v.z; A[11] += F * W2v.w; \
    A[12]+= F * W3v.x; A[13]+= F * W3v.y; A[14] += F * W3v.z; A[15] += F * W3v.w;

__global__ __launch_bounds__(256) void k_gemm1(const float* __restrict__ x,
                                               const float* __restrict__ W1,
                                               float* __restrict__ out) {
    __shared__ float Wl[512 * 16];
    const int tid = threadIdx.x;
    #pragma unroll
    for (int u = 0; u < 32; ++u) {
        int idx = tid + u * 256;          // over W1[512][16]
        int k = idx >> 4, j = idx & 15;
        int slot = (j >> 2) ^ ((k >> 2) & 3);
        Wl[k * 16 + slot * 4 + (j & 3)] = W1[idx];
    }
    __syncthreads();

    const int sub  = tid & 15;            // k-slice owner within quarter-wave
    const int grp  = tid >> 4;            // 0..15: quarter-wave id in block
    const int rbase = blockIdx.x * 64 + grp * 4;

    const int r0 = min(rbase + 0, N_NODES - 1);
    const int r1 = min(rbase + 1, N_NODES - 1);
    const int r2 = min(rbase + 2, N_NODES - 1);
    const int r3 = min(rbase + 3, N_NODES - 1);
    const float* xp0 = x + (size_t)r0 * N_FEAT + sub * 4;
    const float* xp1 = x + (size_t)r1 * N_FEAT + sub * 4;
    const float* xp2 = x + (size_t)r2 * N_FEAT + sub * 4;
    const float* xp3 = x + (size_t)r3 * N_FEAT + sub * 4;

    float a0[16], a1[16], a2[16], a3[16];
    #pragma unroll
    for (int j = 0; j < 16; ++j) { a0[j] = 0.f; a1[j] = 0.f; a2[j] = 0.f; a3[j] = 0.f; }

    const int sw = sub & 3;               // = (k>>2)&3 for this lane's k's

    #pragma unroll 1
    for (int i = 0; i < 8; ++i) {
        const float4 xa = *(const float4*)(xp0 + i * 64);
        const float4 xb = *(const float4*)(xp1 + i * 64);
        const float4 xc = *(const float4*)(xp2 + i * 64);
        const float4 xd = *(const float4*)(xp3 + i * 64);
        const int kb = i * 64 + sub * 4;
        #pragma unroll
        for (int t = 0; t < 4; ++t) {
            const float* wr = &Wl[(kb + t) * 16];
            const float4 w0 = *(const float4*)(wr + ((0 ^ sw) << 2));
            const float4 w1 = *(const float4*)(wr + ((1 ^ sw) << 2));
            const float4 w2 = *(const float4*)(wr + ((2 ^ sw) << 2));
            const float4 w3 = *(const float4*)(wr + ((3 ^ sw) << 2));
            const float fa = (t == 0) ? xa.x : (t == 1) ? xa.y : (t == 2) ? xa.z : xa.w;
            const float fb = (t == 0) ? xb.x : (t == 1) ? xb.y : (t == 2) ? xb.z : xb.w;
            const float fc = (t == 0) ? xc.x : (t == 1) ? xc.y : (t == 2) ? xc.z : xc.w;
            const float fd = (t == 0) ? xd.x : (t == 1) ? xd.y : (t == 2) ? xd.z : xd.w;
            FMA16(a0, fa, w0, w1, w2, w3)
            FMA16(a1, fb, w0, w1, w2, w3)
            FMA16(a2, fc, w0, w1, w2, w3)
            FMA16(a3, fd, w0, w1, w2, w3)
        }
    }

    // butterfly reduce over the 16-lane group (xor bits 0..3 of lane)
    #pragma unroll
    for (int m = 1; m <= 8; m <<= 1) {
        #pragma unroll
        for (int j = 0; j < 16; ++j) {
            a0[j] += __shfl_xor(a0[j], m, 64);
            a1[j] += __shfl_xor(a1[j], m, 64);
            a2[j] += __shfl_xor(a2[j], m, 64);
            a3[j] += __shfl_xor(a3[j], m, 64);
        }
    }

    // lane `sub` writes column j = sub of its 4 rows (static-index select)
    float v0 = a0[0], v1 = a1[0], v2 = a2[0], v3 = a3[0];
    #pragma unroll
    for (int j = 1; j < 16; ++j) {
        const bool p = (sub == j);
        v0 = p ? a0[j] : v0;
        v1 = p ? a1[j] : v1;
        v2 = p ? a2[j] : v2;
        v3 = p ? a3[j] : v3;
    }
    if (rbase + 0 < N_NODES) out[(rbase + 0) * N_HID + sub] = v0;
    if (rbase + 1 < N_NODES) out[(rbase + 1) * N_HID + sub] = v1;
    if (rbase + 2 < N_NODES) out[(rbase + 2) * N_HID + sub] = v2;
    if (rbase + 3 < N_NODES) out[(rbase + 3) * N_HID + sub] = v3;
}

// ======== tier-2 fallback machinery (global hist + scan + random scatter) ========
__global__ __launch_bounds__(256) void k_hist(const int* __restrict__ dst,
                                              int* __restrict__ cnt) {
    int e = blockIdx.x * 256 + threadIdx.x;
    if (e < N_EDGES) atomicAdd(&cnt[dst[e]], 1);
}

__global__ __launch_bounds__(256) void k_scan1(const int* __restrict__ cnt,
                                               int* __restrict__ part,
                                               int* __restrict__ bsum) {
    __shared__ int sh[256];
    const int tid = threadIdx.x;
    const int base = blockIdx.x * SCAN_BLK + tid * 16;
    int v[16];
    int s = 0;
    #pragma unroll
    for (int i = 0; i < 16; ++i) {
        v[i] = (base + i < N_NODES) ? cnt[base + i] : 0;
        s += v[i];
    }
    sh[tid] = s;
    __syncthreads();
    for (int off = 1; off < 256; off <<= 1) {
        int t = (tid >= off) ? sh[tid - off] : 0;
        __syncthreads();
        sh[tid] += t;
        __syncthreads();
    }
    int ex = (tid > 0) ? sh[tid - 1] : 0;
    if (tid == 255) bsum[blockIdx.x] = sh[255];
    int run = ex;
    #pragma unroll
    for (int i = 0; i < 16; ++i) {
        if (base + i < N_NODES) part[base + i] = run;
        run += v[i];
    }
}

__global__ void k_scan2(const int* __restrict__ bsum, int* __restrict__ boffs) {
    if (threadIdx.x == 0) {
        int run = 0;
        for (int i = 0; i < N_SCAN_BLKS; ++i) { boffs[i] = run; run += bsum[i]; }
    }
}

__global__ __launch_bounds__(256) void k_mkstart(const int* __restrict__ part,
                                                 const int* __restrict__ boffs,
                                                 int* __restrict__ start) {
    int n = blockIdx.x * 256 + threadIdx.x;
    if (n < N_NODES) start[n] = part[n] + boffs[n >> 12];
}

__global__ __launch_bounds__(256) void k_scatter(const int* __restrict__ src,
                                                 const int* __restrict__ dst,
                                                 const float* __restrict__ ew,
                                                 const int* __restrict__ start,
                                                 int* __restrict__ cur,
                                                 int2* __restrict__ srt) {
    int e = blockIdx.x * 256 + threadIdx.x;
    if (e >= N_EDGES) return;
    int d = dst[e];
    int pos = start[d] + atomicAdd(&cur[d], 1);
    srt[pos] = make_int2(src[e], __float_as_int(ew[e]));
}

// ======== tier-3 fallback (direct atomic scatter) ========
__global__ __launch_bounds__(256) void k_edge(const int* __restrict__ src,
                                              const int* __restrict__ dst,
                                              const float* __restrict__ ew,
                                              const float* __restrict__ tab,
                                              float* __restrict__ out) {
    int gid = blockIdx.x * 256 + threadIdx.x;
    int e = gid >> 2;
    if (e >= N_EDGES) return;
    int j4 = (gid & 3) << 2;
    int s = src[e];
    int d = dst[e];
    float w = ew[e];
    const float4 v = *(const float4*)&tab[s * N_HID + j4];
    float* o = &out[d * N_HID + j4];
    atomicAdd(o + 0, v.x * w);
    atomicAdd(o + 1, v.y * w);
    atomicAdd(o + 2, v.z * w);
    atomicAdd(o + 3, v.w * w);
}

__global__ void k_relu_bias(float* __restrict__ h, const float* __restrict__ b1) {
    int i = blockIdx.x * 256 + threadIdx.x;
    if (i >= N_NODES * 4) return;
    float4 v = ((float4*)h)[i];
    int jb = (i & 3) << 2;
    v.x = fmaxf(v.x + b1[jb + 0], 0.f);
    v.y = fmaxf(v.y + b1[jb + 1], 0.f);
    v.z = fmaxf(v.z + b1[jb + 2], 0.f);
    v.w = fmaxf(v.w + b1[jb + 3], 0.f);
    ((float4*)h)[i] = v;
}

// ---------------- out = log_softmax(agg2 @ W2 + b2) ----------------
__global__ __launch_bounds__(256) void k_out(const float* __restrict__ agg2,
                                             const float* __restrict__ W2,
                                             const float* __restrict__ b2,
                                             float* __restrict__ out) {
    int row  = (blockIdx.x * 256 + threadIdx.x) >> 6;
    int lane = threadIdx.x & 63;
    if (row >= N_NODES) return;

    const float* a = &agg2[row * N_HID];
    float av[16];
    #pragma unroll
    for (int k = 0; k < 16; k += 4) {
        float4 t = *(const float4*)&a[k];
        av[k + 0] = t.x; av[k + 1] = t.y; av[k + 2] = t.z; av[k + 3] = t.w;
    }

    int c = (lane < N_CLS) ? lane : 0;
    float acc = b2[c];
    #pragma unroll
    for (int k = 0; k < 16; ++k)
        acc = fmaf(av[k], W2[k * N_CLS + c], acc);

    float mval = (lane < N_CLS) ? acc : -INFINITY;
    #pragma unroll
    for (int m = 32; m; m >>= 1) mval = fmaxf(mval, __shfl_xor(mval, m, 64));
    float ex = (lane < N_CLS) ? expf(acc - mval) : 0.f;
    float s = ex;
    #pragma unroll
    for (int m = 32; m; m >>= 1) s += __shfl_xor(s, m, 64);
    float ls = logf(s);
    if (lane < N_CLS) out[row * N_CLS + lane] = acc - mval - ls;
}

extern "C" void kernel_launch(void* const* d_in, const int* in_sizes, int n_in,
                              void* d_out, int out_size, void* d_ws, size_t ws_size,
                              hipStream_t stream) {
    const float* x    = (const float*)d_in[0];
    const int*   esrc = (const int*)  d_in[1];
    const int*   edst = (const int*)  d_in[2];
    const float* ew   = (const float*)d_in[3];
    const float* W1   = (const float*)d_in[4];
    const float* b1   = (const float*)d_in[5];
    const float* W2   = (const float*)d_in[6];
    const float* b2   = (const float*)d_in[7];
    float* out = (float*)d_out;

    // ---- tier-1 workspace layout, 4-byte units ----
    // bin  : NB*CAP int2 = 27.3 MB — dead after k_place2; buf0/buf1 alias here
    // srt  : 6.4M ints (25.6 MB)
    // start: CNT_PAD; cnt: CNT_PAD; curb: NB_PAD; bbase: NB_PAD
    int* ws = (int*)d_ws;
    int2*  bin  = (int2*)ws;
    float* buf0 = (float*)ws;                              // alias of bin
    float* buf1 = buf0 + (size_t)N_NODES * N_HID;          // alias of bin (+6.4MB)
    int2*  srt  = (int2*)(ws + 2 * (size_t)NB * CAP);
    int*   start = ws + 2 * (size_t)NB * CAP + 2 * (size_t)N_EDGES;
    int*   cnt   = start + CNT_PAD;
    int*   curb  = cnt + CNT_PAD;
    int*   bbase = curb + NB_PAD;
    const size_t need1 = ((size_t)(bbase + NB_PAD) - (size_t)d_ws);

    const int n4 = N_NODES * 4;
    const int zgrid = (n4 + 255) / 256;
    const int egrid = (N_EDGES + 255) / 256;

    if (ws_size >= need1) {
        // ---- tier 1: bucket-local CSR build + 32-lane agg ----
        k_zero_i<<<1, 256, 0, stream>>>(curb, NB_PAD);
        k_bin<<<(N_EDGES + BIN_CHUNK - 1) / BIN_CHUNK, 256, 0, stream>>>(
            esrc, edst, ew, curb, bin);
        k_bscan<<<1, 64, 0, stream>>>(curb, bbase);
        k_place2<<<NB, 256, 0, stream>>>(curb, bbase, bin, srt, start, cnt);
        // bin region is now dead -> buf0/buf1 reuse it
        k_gemm1<<<(N_NODES + 63) / 64, 256, 0, stream>>>(x, W1, buf0);
        k_agg<1><<<(N_NODES * 32 + 255) / 256, 256, 0, stream>>>(
            start, cnt, srt, buf0, b1, buf1);
        k_agg<0><<<(N_NODES * 32 + 255) / 256, 256, 0, stream>>>(
            start, cnt, srt, buf1, b1 /*unused*/, buf0);
        k_out<<<(N_NODES + 3) / 4, 256, 0, stream>>>(buf0, W2, b2, out);
        return;
    }

    // ---- tier 2: global hist + scan + random scatter CSR (~40 MB) ----
    {
        int2*  srt2  = (int2*)ws;
        float* f0 = (float*)(ws + 2 * (size_t)N_EDGES);
        float* f1 = f0 + (size_t)N_NODES * N_HID;
        int*   cnt2 = (int*)(f1 + (size_t)N_NODES * N_HID);
        int*   cur2 = cnt2 + CNT_PAD;
        int*   part2 = cur2 + CNT_PAD;
        int*   start2 = part2 + CNT_PAD;
        int*   bsum2 = start2 + CNT_PAD;
        int*   boffs2 = bsum2 + 64;
        const size_t need2 = ((size_t)(boffs2 + 64) - (size_t)d_ws);
        if (ws_size >= need2) {
            k_zero_i<<<(2 * CNT_PAD + 255) / 256, 256, 0, stream>>>(cnt2, 2 * CNT_PAD);
            k_hist<<<egrid, 256, 0, stream>>>(edst, cnt2);
            k_scan1<<<N_SCAN_BLKS, 256, 0, stream>>>(cnt2, part2, bsum2);
            k_scan2<<<1, 64, 0, stream>>>(bsum2, boffs2);
            k_mkstart<<<(N_NODES + 255) / 256, 256, 0, stream>>>(part2, boffs2, start2);
            k_scatter<<<egrid, 256, 0, stream>>>(esrc, edst, ew, start2, cur2, srt2);
            k_gemm1<<<(N_NODES + 63) / 64, 256, 0, stream>>>(x, W1, f0);
            k_agg<1><<<(N_NODES * 32 + 255) / 256, 256, 0, stream>>>(
                start2, cnt2, srt2, f0, b1, f1);
            k_agg<0><<<(N_NODES * 32 + 255) / 256, 256, 0, stream>>>(
                start2, cnt2, srt2, f1, b1 /*unused*/, f0);
            k_out<<<(N_NODES + 3) / 4, 256, 0, stream>>>(f0, W2, b2, out);
            return;
        }
    }

    // ---- tier 3: atomic path ----
    {
        float* fb0 = (float*)d_ws;
        float* fb1 = fb0 + (size_t)N_NODES * N_HID;
        k_zero<<<zgrid, 256, 0, stream>>>((float4*)fb1, n4);
        k_gemm1<<<(N_NODES + 63) / 64, 256, 0, stream>>>(x, W1, fb0);
        k_edge<<<(N_EDGES * 4 + 255) / 256, 256, 0, stream>>>(esrc, edst, ew, fb0, fb1);
        k_relu_bias<<<zgrid, 256, 0, stream>>>(fb1, b1);
        k_zero<<<zgrid, 256, 0, stream>>>((float4*)fb0, n4);
        k_edge<<<(N_EDGES * 4 + 255) / 256, 256, 0, stream>>>(esrc, edst, ew, fb1, fb0);
        k_out<<<(N_NODES + 3) / 4, 256, 0, stream>>>(fb0, W2, b2, out);
    }
}